// Round 11
// baseline (132.709 us; speedup 1.0000x reference)
//
#include <hip/hip_runtime.h>
#include <cstdint>

// LCA model constants
#define T_STEPS 3000
#define S_SIMS  1000
#define D_DIM   16
#define NJ      (S_SIMS * D_DIM)          // 16000 flat (s,d) rows
#define ROW     (T_STEPS + 1)             // 3001 outputs per row
#define HALF_OUT ((long long)NJ * ROW)

#define NSIMB  250                        // blocks: 4 sims each, 64 rows each
#define NPROD  7                          // producer waves (r6-proven)
#define DEPTH  32                         // LDS noise ring slots (r6-proven)
#define BATCH  8                          // consumer speculation batch (r6-proven)
#define PAD_FLOATS 13000                  // LDS pad -> ~84KB total -> 1 block/CU
#define SQSTEP 0.03162277660168379f       // sqrt(0.001)

// 4-float vector with DEcreased (4B) alignment: rows start at jr*3001 floats,
// only dword-aligned. gfx9+ global dwordx4 needs only dword alignment; clang
// permits reduced alignment on typedefs.
typedef float v4f __attribute__((ext_vector_type(4)));
typedef v4f uv4f __attribute__((aligned(4)));

__device__ float g_ws_pre[(size_t)T_STEPS * NJ];  // [t][j] prefix only

// ---------------------------------------------------------------------------
// Threefry-2x32 (20 rounds), bit-exact vs jax._src.prng (partitionable mode)
// ---------------------------------------------------------------------------
__device__ __forceinline__ uint32_t rotl32(uint32_t v, uint32_t d) {
  return (v << d) | (v >> (32u - d));
}
__device__ __forceinline__ void threefry2x32(uint32_t k0, uint32_t k1,
                                             uint32_t& x0, uint32_t& x1) {
  uint32_t k2 = k0 ^ k1 ^ 0x1BD11BDAu;
  x0 += k0; x1 += k1;
#define TFR(r) { x0 += x1; x1 = rotl32(x1, r); x1 ^= x0; }
  TFR(13u) TFR(15u) TFR(26u) TFR(6u)
  x0 += k1; x1 += k2 + 1u;
  TFR(17u) TFR(29u) TFR(16u) TFR(24u)
  x0 += k2; x1 += k0 + 2u;
  TFR(13u) TFR(15u) TFR(26u) TFR(6u)
  x0 += k0; x1 += k1 + 3u;
  TFR(17u) TFR(29u) TFR(16u) TFR(24u)
  x0 += k1; x1 += k2 + 4u;
  TFR(13u) TFR(15u) TFR(26u) TFR(6u)
  x0 += k2; x1 += k0 + 5u;
#undef TFR
}

// bits -> N(0,1): jax.random.normal f32 path (XLA ErfInv32 / Giles), with
// log1p(-u*u) = ln2*log2((1-u)(1+u)) via HW log (validated r6: absmax 0.002).
__device__ __forceinline__ float bits_to_normal(uint32_t bits) {
  uint32_t fb = (bits >> 9) | 0x3f800000u;
  float f = __uint_as_float(fb) - 1.0f;
  const float lo = -0.99999994f;
  float u = f * 2.0f + lo;
  u = fmaxf(lo, u);
  float w = -0.6931471805599453f * __log2f((1.0f - u) * (1.0f + u));
  float p;
  if (w < 5.0f) {
    w = w - 2.5f;
    p = 2.81022636e-08f;
    p = fmaf(p, w, 3.43273939e-07f);
    p = fmaf(p, w, -3.5233877e-06f);
    p = fmaf(p, w, -4.39150654e-06f);
    p = fmaf(p, w, 0.00021858087f);
    p = fmaf(p, w, -0.00125372503f);
    p = fmaf(p, w, -0.00417768164f);
    p = fmaf(p, w, 0.246640727f);
    p = fmaf(p, w, 1.50140941f);
  } else {
    w = sqrtf(w) - 3.0f;
    p = -0.000200214257f;
    p = fmaf(p, w, 0.000100950558f);
    p = fmaf(p, w, 0.00134934322f);
    p = fmaf(p, w, -0.00367342844f);
    p = fmaf(p, w, 0.00573950773f);
    p = fmaf(p, w, -0.0076224613f);
    p = fmaf(p, w, 0.00943887047f);
    p = fmaf(p, w, 1.00167406f);
    p = fmaf(p, w, 2.83297682f);
  }
  return 1.41421356237f * (p * u);
}

// ---------------------------------------------------------------------------
// DPP reductions within each 16-lane row (one sim).
// ---------------------------------------------------------------------------
template <int CTRL>
__device__ __forceinline__ float dpp_movf(float v) {
  return __int_as_float(
      __builtin_amdgcn_update_dpp(0, __float_as_int(v), CTRL, 0xF, 0xF, true));
}
__device__ __forceinline__ float row16_sum(float a) {
  float s = a;
  s += dpp_movf<0xB1>(s);
  s += dpp_movf<0x4E>(s);
  s += dpp_movf<0x124>(s);
  s += dpp_movf<0x128>(s);
  return s;
}
__device__ __forceinline__ float row16_max(float a) {  // a >= 0
  float m = a;
  m = fmaxf(m, dpp_movf<0xB1>(m));
  m = fmaxf(m, dpp_movf<0x4E>(m));
  m = fmaxf(m, dpp_movf<0x124>(m));
  m = fmaxf(m, dpp_movf<0x128>(m));
  return m;
}

// ---------------------------------------------------------------------------
// Single kernel: keys prologue (LDS) -> r6 producer-consumer sim (verbatim
// r10, 72us critical) -> block-cooperative TRANSPOSED self-fill of the
// block's own 64 rows (LDS 64x65 tile aliased onto dead sh_keys; coalesced
// ws reads, packed 4-float stores). No cross-block communication.
// ---------------------------------------------------------------------------
__global__ __launch_bounds__(512) void lca_kernel(const float* __restrict__ ff,
                                                  float* __restrict__ out) {
  __shared__ uint2 sh_keys[T_STEPS];             // 24.0 KB; reused as fill tile
  __shared__ float sh_nbuf[DEPTH][64];           //  8.2 KB
  __shared__ float sh_pad[PAD_FLOATS];           // 52.0 KB occupancy pad
  __shared__ float sh_vlast[64];
  __shared__ volatile unsigned sh_prodc[NPROD];
  __shared__ volatile unsigned sh_cons;
  __shared__ volatile unsigned sh_done;
  __shared__ int sh_tf[4];

  const int tid  = threadIdx.x;
  const int lane = tid & 63;
  const int wid  = tid >> 6;
  const int jb   = blockIdx.x * 64;
  const int j    = jb + lane;                    // s = j>>4, d = j&15

  // ---- prologue: all 3000 step keys into LDS (partitionable fold) ----
  for (int i = tid; i < T_STEPS; i += 512) {
    uint32_t x0 = 0u, x1 = (uint32_t)i;
    threefry2x32(0u, 42u, x0, x1);
    sh_keys[i] = make_uint2(x0, x1);
  }
  { volatile float* vp = sh_pad; vp[tid] = 0.0f; }   // keep pad alive
  if (tid < NPROD) sh_prodc[tid] = 0u;
  if (tid == 0) { sh_cons = 0u; sh_done = 0u; }
  __syncthreads();

  if (wid == 0) {
    // ============ consumer: LCA dynamics, batch-8 speculative (r6) ==========
    __builtin_amdgcn_s_setprio(1);
    const float ffv = ff[j];
    float pre = 0.0f, act = 0.0f;
    bool dead = false;
    int my_tf = T_STEPS;
    unsigned Rc = 0;   // steps < Rc are known produced

#define ENSURE(x)                                                     \
    while (Rc <= (unsigned)(x)) {                                     \
      unsigned mn = 0xffffffffu;                                      \
      for (int p_ = 0; p_ < NPROD; ++p_) {                            \
        unsigned lim = (unsigned)p_ + (unsigned)NPROD * sh_prodc[p_]; \
        if (lim < mn) mn = lim;                                       \
      }                                                               \
      Rc = mn;                                                        \
      if (Rc <= (unsigned)(x)) __builtin_amdgcn_s_sleep(2);           \
    }

    float n[BATCH], nn[BATCH], a[BATCH];
    ENSURE(BATCH - 1);
#pragma unroll
    for (int k = 0; k < BATCH; ++k) n[k] = sh_nbuf[k][lane];

    int t0 = 0;
    while (true) {
      if (lane == 0) sh_cons = (unsigned)(t0 + BATCH);
      const bool more = (t0 + BATCH < T_STEPS);
      if (more) {
        ENSURE(t0 + 2 * BATCH - 1);
#pragma unroll
        for (int k = 0; k < BATCH; ++k)
          nn[k] = sh_nbuf[(t0 + BATCH + k) & (DEPTH - 1)][lane];
      }

      float bmax = 0.0f;
      float* __restrict__ wsp = g_ws_pre + (size_t)t0 * NJ + j;
#pragma unroll
      for (int k = 0; k < BATCH; ++k) {
        float s  = row16_sum(act);
        float e1 = fmaf(-0.1f, pre, ffv);          // ff - leak*pre
        float e2 = fmaf(-0.1f, s - act, e1);       // - competition*(sum-self)
        pre = fmaf(e2, 0.01f, pre);                // + expr*dt
        pre = fmaf(n[k], SQSTEP, pre);             // + dw*sqrt(0.001)
        act = fmaxf(pre, 0.0f);
        a[k] = act;
        bmax = fmaxf(bmax, act);
        if (!dead) wsp[(size_t)k * NJ] = pre;
      }

      if (__any(bmax >= 1.0f)) {                   // rare: <=4x per wave
        bool found = dead;
        int ctf = 0;
#pragma unroll
        for (int k = 0; k < BATCH; ++k) {
          float m = row16_max(a[k]);               // row-uniform
          if (!found && m >= 1.0f) { found = true; ctf = t0 + k + 1; }
        }
        if (found && !dead) {                      // this row just crossed
          dead = true;
          my_tf = ctf;
          pre = -1e30f;                            // relu pins act=0 forever
          act = 0.0f;
        }
        if (__all(dead)) break;
      }

      if (!more) break;
#pragma unroll
      for (int k = 0; k < BATCH; ++k) n[k] = nn[k];
      t0 += BATCH;
    }
#undef ENSURE
    if ((lane & 15) == 0) sh_tf[lane >> 4] = my_tf;  // row-uniform, 1<=tf<=3000
    if (lane == 0) sh_done = 1u;
    __builtin_amdgcn_s_setprio(0);
  } else {
    // ============ producers: noise for t ≡ p (mod NPROD) (r6) ===============
    const int p = wid - 1;
    unsigned count = 0;
    bool quit = false;
    for (int t = p; t < T_STEPS; t += NPROD) {
      if (sh_done) break;
      uint2 k = sh_keys[t];
      uint32_t x0 = 0u, x1 = (uint32_t)j;
      threefry2x32(k.x, k.y, x0, x1);
      float nv = bits_to_normal(x0 ^ x1);
      if (t >= DEPTH) {
        while (true) {
          if (sh_done) { quit = true; break; }
          unsigned pc = sh_cons;
          if ((unsigned)t <= pc + (DEPTH - 1)) break;
          __builtin_amdgcn_s_sleep(4);
        }
        if (quit) break;
      }
      sh_nbuf[t & (DEPTH - 1)][lane] = nv;
      asm volatile("s_waitcnt lgkmcnt(0)" ::: "memory");
      ++count;
      if (lane == 0) sh_prodc[p] = count;
    }
  }

  __syncthreads();   // sh_tf visible; consumer's ws writes drained; keys dead

  // ================= block-cooperative transposed self-fill =================
  // prep: per-row vlast + idx0 zeros
  if (tid < 64) {
    int tfr = sh_tf[tid >> 4];
    sh_vlast[tid] = g_ws_pre[(size_t)(tfr - 1) * NJ + jb + tid];
    float* po = out + (size_t)(jb + tid) * ROW;
    po[0] = 0.0f;
    po[HALF_OUT] = 0.0f;
  }
  const int maxtf = max(max(sh_tf[0], sh_tf[1]), max(sh_tf[2], sh_tf[3]));
  float* sh_tilef = (float*)sh_keys;               // [64][65] = 16.6 KB < 24 KB
#define TILE(tl, r) sh_tilef[(tl) * 65 + (r)]

  // Phase A: t-tiles [tt0, tt0+64). Load coalesced along j, store along t.
  const float* __restrict__ wsb = g_ws_pre + jb;
  for (int tt0 = 0; tt0 < maxtf; tt0 += 64) {
    __syncthreads();                               // tile free (also: prep visible)
#pragma unroll
    for (int q = 0; q < 8; ++q) {
      int t = tt0 + wid * 8 + q;
      float v = 0.0f;
      if (t < T_STEPS) v = wsb[(size_t)t * NJ + lane];   // 256B coalesced
      TILE(wid * 8 + q, lane) = v;
    }
    __syncthreads();
#pragma unroll
    for (int pass = 0; pass < 2; ++pass) {
      const int r   = wid * 8 + pass * 4 + (lane >> 4);  // 4 rows per pass
      const int tq  = lane & 15;
      const int jr  = jb + r;
      const int tfr = sh_tf[r >> 4];
      const float vl = sh_vlast[r];
      const int idx = tt0 + 1 + 4 * tq;
      uv4f vv, av;
#pragma unroll
      for (int i = 0; i < 4; ++i) {
        float tv = TILE(4 * tq + i, r);            // bank(4tq+i+r): 2-way, free
        float v  = (idx + i <= tfr) ? tv : vl;
        vv[i] = v;
        av[i] = fmaxf(v, 0.0f);
      }
      float* po = out + (size_t)jr * ROW;
      float* ao = po + HALF_OUT;
      if (idx + 3 <= T_STEPS) {
        *(uv4f*)(po + idx) = vv;
        *(uv4f*)(ao + idx) = av;
      } else {
#pragma unroll
        for (int i = 0; i < 4; ++i)
          if (idx + i <= T_STEPS) { po[idx + i] = vv[i]; ao[idx + i] = av[i]; }
      }
    }
  }

  // Phase B: pure frozen tail for all rows, idx in [idxB, 3000]
  const int idxB = (((maxtf + 63) >> 6) << 6) + 1;
  if (idxB <= T_STEPS) {
    const int span  = T_STEPS - idxB + 1;
    const int nquad = span >> 2;
    const int rem   = span & 3;
    const int rem_start = idxB + (nquad << 2);
#pragma unroll
    for (int pass = 0; pass < 2; ++pass) {
      const int r  = wid * 8 + pass * 4 + (lane >> 4);
      const int jr = jb + r;
      const float vl = sh_vlast[r];
      const float va = fmaxf(vl, 0.0f);
      uv4f pv = {vl, vl, vl, vl};
      uv4f av = {va, va, va, va};
      float* po = out + (size_t)jr * ROW;
      float* ao = po + HALF_OUT;
      for (int qi = (lane & 15); qi < nquad; qi += 16) {
        const int idx = idxB + 4 * qi;
        *(uv4f*)(po + idx) = pv;
        *(uv4f*)(ao + idx) = av;
      }
      if ((lane & 15) < rem) {
        const int idx = rem_start + (lane & 15);
        po[idx] = vl;
        ao[idx] = va;
      }
    }
  }
#undef TILE
}

// ---------------------------------------------------------------------------
extern "C" void kernel_launch(void* const* d_in, const int* in_sizes, int n_in,
                              void* d_out, int out_size, void* d_ws, size_t ws_size,
                              hipStream_t stream) {
  const float* ff = (const float*)d_in[0];
  float* out = (float*)d_out;

  lca_kernel<<<dim3(NSIMB), dim3(512), 0, stream>>>(ff, out);
}

// Round 12
// 132.390 us; speedup vs baseline: 1.0024x; 1.0024x over previous
//
#include <hip/hip_runtime.h>
#include <cstdint>

// LCA model constants
#define T_STEPS 3000
#define S_SIMS  1000
#define D_DIM   16
#define NJ      (S_SIMS * D_DIM)          // 16000 flat (s,d) rows
#define ROW     (T_STEPS + 1)             // 3001 outputs per row
#define HALF_OUT ((long long)NJ * ROW)

#define NSIMB  250                        // blocks: 4 sims each, 64 rows each
#define NPROD  7                          // producer waves (r6-proven)
#define DEPTH  32                         // LDS noise ring slots (r6-proven)
#define BATCH  8                          // consumer speculation batch (r6-proven)
#define PAD_FLOATS 13000                  // LDS pad -> ~84KB total -> 1 block/CU
#define SQSTEP 0.03162277660168379f       // sqrt(0.001)

typedef float v4f __attribute__((ext_vector_type(4)));  // natural 16B alignment

__device__ float g_ws_pre[(size_t)T_STEPS * NJ];  // [t][j] prefix only

// ---------------------------------------------------------------------------
// Threefry-2x32 (20 rounds), bit-exact vs jax._src.prng (partitionable mode)
// ---------------------------------------------------------------------------
__device__ __forceinline__ uint32_t rotl32(uint32_t v, uint32_t d) {
  return (v << d) | (v >> (32u - d));
}
__device__ __forceinline__ void threefry2x32(uint32_t k0, uint32_t k1,
                                             uint32_t& x0, uint32_t& x1) {
  uint32_t k2 = k0 ^ k1 ^ 0x1BD11BDAu;
  x0 += k0; x1 += k1;
#define TFR(r) { x0 += x1; x1 = rotl32(x1, r); x1 ^= x0; }
  TFR(13u) TFR(15u) TFR(26u) TFR(6u)
  x0 += k1; x1 += k2 + 1u;
  TFR(17u) TFR(29u) TFR(16u) TFR(24u)
  x0 += k2; x1 += k0 + 2u;
  TFR(13u) TFR(15u) TFR(26u) TFR(6u)
  x0 += k0; x1 += k1 + 3u;
  TFR(17u) TFR(29u) TFR(16u) TFR(24u)
  x0 += k1; x1 += k2 + 4u;
  TFR(13u) TFR(15u) TFR(26u) TFR(6u)
  x0 += k2; x1 += k0 + 5u;
#undef TFR
}

// bits -> N(0,1): jax.random.normal f32 path (XLA ErfInv32 / Giles), with
// log1p(-u*u) = ln2*log2((1-u)(1+u)) via HW log (validated r6: absmax 0.002).
__device__ __forceinline__ float bits_to_normal(uint32_t bits) {
  uint32_t fb = (bits >> 9) | 0x3f800000u;
  float f = __uint_as_float(fb) - 1.0f;
  const float lo = -0.99999994f;
  float u = f * 2.0f + lo;
  u = fmaxf(lo, u);
  float w = -0.6931471805599453f * __log2f((1.0f - u) * (1.0f + u));
  float p;
  if (w < 5.0f) {
    w = w - 2.5f;
    p = 2.81022636e-08f;
    p = fmaf(p, w, 3.43273939e-07f);
    p = fmaf(p, w, -3.5233877e-06f);
    p = fmaf(p, w, -4.39150654e-06f);
    p = fmaf(p, w, 0.00021858087f);
    p = fmaf(p, w, -0.00125372503f);
    p = fmaf(p, w, -0.00417768164f);
    p = fmaf(p, w, 0.246640727f);
    p = fmaf(p, w, 1.50140941f);
  } else {
    w = sqrtf(w) - 3.0f;
    p = -0.000200214257f;
    p = fmaf(p, w, 0.000100950558f);
    p = fmaf(p, w, 0.00134934322f);
    p = fmaf(p, w, -0.00367342844f);
    p = fmaf(p, w, 0.00573950773f);
    p = fmaf(p, w, -0.0076224613f);
    p = fmaf(p, w, 0.00943887047f);
    p = fmaf(p, w, 1.00167406f);
    p = fmaf(p, w, 2.83297682f);
  }
  return 1.41421356237f * (p * u);
}

// ---------------------------------------------------------------------------
// DPP reductions within each 16-lane row (one sim).
// ---------------------------------------------------------------------------
template <int CTRL>
__device__ __forceinline__ float dpp_movf(float v) {
  return __int_as_float(
      __builtin_amdgcn_update_dpp(0, __float_as_int(v), CTRL, 0xF, 0xF, true));
}
__device__ __forceinline__ float row16_sum(float a) {
  float s = a;
  s += dpp_movf<0xB1>(s);
  s += dpp_movf<0x4E>(s);
  s += dpp_movf<0x124>(s);
  s += dpp_movf<0x128>(s);
  return s;
}
__device__ __forceinline__ float row16_max(float a) {  // a >= 0
  float m = a;
  m = fmaxf(m, dpp_movf<0xB1>(m));
  m = fmaxf(m, dpp_movf<0x4E>(m));
  m = fmaxf(m, dpp_movf<0x124>(m));
  m = fmaxf(m, dpp_movf<0x128>(m));
  return m;
}

// ---------------------------------------------------------------------------
// Single kernel: keys prologue (LDS) -> r6 producer-consumer sim (verbatim
// r10, 72us critical) -> per-wave ALIGNED-float4 self-fill of the wave's own
// 8 rows (no LDS, no barriers; alignment constructed per row since ROW is
// odd). tf is wave-uniform (8 rows = half of one 16-row sim).
// ---------------------------------------------------------------------------
__global__ __launch_bounds__(512) void lca_kernel(const float* __restrict__ ff,
                                                  float* __restrict__ out) {
  __shared__ uint2 sh_keys[T_STEPS];             // 24.0 KB
  __shared__ float sh_nbuf[DEPTH][64];           //  8.2 KB
  __shared__ float sh_pad[PAD_FLOATS];           // 52.0 KB occupancy pad
  __shared__ volatile unsigned sh_prodc[NPROD];
  __shared__ volatile unsigned sh_cons;
  __shared__ volatile unsigned sh_done;
  __shared__ int sh_tf[4];

  const int tid  = threadIdx.x;
  const int lane = tid & 63;
  const int wid  = tid >> 6;
  const int jb   = blockIdx.x * 64;
  const int j    = jb + lane;                    // s = j>>4, d = j&15

  // ---- prologue: all 3000 step keys into LDS (partitionable fold) ----
  for (int i = tid; i < T_STEPS; i += 512) {
    uint32_t x0 = 0u, x1 = (uint32_t)i;
    threefry2x32(0u, 42u, x0, x1);
    sh_keys[i] = make_uint2(x0, x1);
  }
  { volatile float* vp = sh_pad; vp[tid] = 0.0f; }   // keep pad alive
  if (tid < NPROD) sh_prodc[tid] = 0u;
  if (tid == 0) { sh_cons = 0u; sh_done = 0u; }
  __syncthreads();

  if (wid == 0) {
    // ============ consumer: LCA dynamics, batch-8 speculative (r6) ==========
    __builtin_amdgcn_s_setprio(1);
    const float ffv = ff[j];
    float pre = 0.0f, act = 0.0f;
    bool dead = false;
    int my_tf = T_STEPS;
    unsigned Rc = 0;   // steps < Rc are known produced

#define ENSURE(x)                                                     \
    while (Rc <= (unsigned)(x)) {                                     \
      unsigned mn = 0xffffffffu;                                      \
      for (int p_ = 0; p_ < NPROD; ++p_) {                            \
        unsigned lim = (unsigned)p_ + (unsigned)NPROD * sh_prodc[p_]; \
        if (lim < mn) mn = lim;                                       \
      }                                                               \
      Rc = mn;                                                        \
      if (Rc <= (unsigned)(x)) __builtin_amdgcn_s_sleep(2);           \
    }

    float n[BATCH], nn[BATCH], a[BATCH];
    ENSURE(BATCH - 1);
#pragma unroll
    for (int k = 0; k < BATCH; ++k) n[k] = sh_nbuf[k][lane];

    int t0 = 0;
    while (true) {
      if (lane == 0) sh_cons = (unsigned)(t0 + BATCH);
      const bool more = (t0 + BATCH < T_STEPS);
      if (more) {
        ENSURE(t0 + 2 * BATCH - 1);
#pragma unroll
        for (int k = 0; k < BATCH; ++k)
          nn[k] = sh_nbuf[(t0 + BATCH + k) & (DEPTH - 1)][lane];
      }

      float bmax = 0.0f;
      float* __restrict__ wsp = g_ws_pre + (size_t)t0 * NJ + j;
#pragma unroll
      for (int k = 0; k < BATCH; ++k) {
        float s  = row16_sum(act);
        float e1 = fmaf(-0.1f, pre, ffv);          // ff - leak*pre
        float e2 = fmaf(-0.1f, s - act, e1);       // - competition*(sum-self)
        pre = fmaf(e2, 0.01f, pre);                // + expr*dt
        pre = fmaf(n[k], SQSTEP, pre);             // + dw*sqrt(0.001)
        act = fmaxf(pre, 0.0f);
        a[k] = act;
        bmax = fmaxf(bmax, act);
        if (!dead) wsp[(size_t)k * NJ] = pre;
      }

      if (__any(bmax >= 1.0f)) {                   // rare: <=4x per wave
        bool found = dead;
        int ctf = 0;
#pragma unroll
        for (int k = 0; k < BATCH; ++k) {
          float m = row16_max(a[k]);               // row-uniform
          if (!found && m >= 1.0f) { found = true; ctf = t0 + k + 1; }
        }
        if (found && !dead) {                      // this row just crossed
          dead = true;
          my_tf = ctf;
          pre = -1e30f;                            // relu pins act=0 forever
          act = 0.0f;
        }
        if (__all(dead)) break;
      }

      if (!more) break;
#pragma unroll
      for (int k = 0; k < BATCH; ++k) n[k] = nn[k];
      t0 += BATCH;
    }
#undef ENSURE
    if ((lane & 15) == 0) sh_tf[lane >> 4] = my_tf;  // row-uniform, 1<=tf<=3000
    if (lane == 0) sh_done = 1u;
    __builtin_amdgcn_s_setprio(0);
  } else {
    // ============ producers: noise for t ≡ p (mod NPROD) (r6) ===============
    const int p = wid - 1;
    unsigned count = 0;
    bool quit = false;
    for (int t = p; t < T_STEPS; t += NPROD) {
      if (sh_done) break;
      uint2 k = sh_keys[t];
      uint32_t x0 = 0u, x1 = (uint32_t)j;
      threefry2x32(k.x, k.y, x0, x1);
      float nv = bits_to_normal(x0 ^ x1);
      if (t >= DEPTH) {
        while (true) {
          if (sh_done) { quit = true; break; }
          unsigned pc = sh_cons;
          if ((unsigned)t <= pc + (DEPTH - 1)) break;
          __builtin_amdgcn_s_sleep(4);
        }
        if (quit) break;
      }
      sh_nbuf[t & (DEPTH - 1)][lane] = nv;
      asm volatile("s_waitcnt lgkmcnt(0)" ::: "memory");
      ++count;
      if (lane == 0) sh_prodc[p] = count;
    }
  }

  __syncthreads();   // sh_tf visible; consumer's ws writes drained (vmcnt(0))

  // ============ per-wave aligned-float4 self-fill of 8 own rows =============
  // Wave wid owns rows r0..r0+7 (half of sim group r0>>4) -> tf uniform.
  // Values: out[idx] = idx==0 ? 0 : ws[min(idx-1, tf-1)]  (== r10 semantics).
  const int r0   = wid * 8;
  const int jr0  = jb + r0;
  const int tf   = sh_tf[r0 >> 4];
  const int tfm1 = tf - 1;

  // Per-row specials: idx 0, unaligned head [1,Ar), tail remainder (<=3 each)
  if (lane < 8) {
    const int jr = jr0 + lane;
    float* po = out + (size_t)jr * ROW;
    float* ao = po + HALF_OUT;
    po[0] = 0.0f; ao[0] = 0.0f;
    int Ar = (4 - (jr & 3)) & 3; if (Ar == 0) Ar = 4;
    const int nq = (T_STEPS - Ar + 1) >> 2;
    for (int idx = 1; idx < Ar; ++idx) {
      int te = idx - 1; te = te < tfm1 ? te : tfm1;
      float v = g_ws_pre[(size_t)te * NJ + jr];
      po[idx] = v; ao[idx] = fmaxf(v, 0.0f);
    }
    for (int idx = Ar + (nq << 2); idx <= T_STEPS; ++idx) {
      int te = idx - 1; te = te < tfm1 ? te : tfm1;
      float v = g_ws_pre[(size_t)te * NJ + jr];
      po[idx] = v; ao[idx] = fmaxf(v, 0.0f);
    }
  }

  // Main: chunk-major (w), row-inner (r): 8 rows reuse the same ws cachelines
  // within a 16KB L1 window. Stores are 16B-aligned by construction:
  // (jr*ROW + Ar + 4k) mod 4 == (jr + Ar) mod 4 == 0.   Beyond-tf gathers
  // collapse to a uniform broadcast of ws[tfm1] (L1-hit) -> tails ~pure-store.
  for (int w = 0; w < 12; ++w) {
    for (int r = 0; r < 8; ++r) {
      const int jr = jr0 + r;
      int Ar = (4 - (jr & 3)) & 3; if (Ar == 0) Ar = 4;
      const int nq = (T_STEPS - Ar + 1) >> 2;
      const int k  = (w << 6) + lane;
      if (k >= nq) continue;
      const int idx = Ar + (k << 2);
      const float* __restrict__ wsj = g_ws_pre + jr;
      v4f vv, av;
#pragma unroll
      for (int i = 0; i < 4; ++i) {
        int te = idx + i - 1; te = te < tfm1 ? te : tfm1;
        float v = wsj[(size_t)te * NJ];
        vv[i] = v; av[i] = fmaxf(v, 0.0f);
      }
      float* po = out + (size_t)jr * ROW;
      *(v4f*)(po + idx) = vv;                      // global_store_dwordx4
      *(v4f*)(po + HALF_OUT + idx) = av;
    }
  }
}

// ---------------------------------------------------------------------------
extern "C" void kernel_launch(void* const* d_in, const int* in_sizes, int n_in,
                              void* d_out, int out_size, void* d_ws, size_t ws_size,
                              hipStream_t stream) {
  const float* ff = (const float*)d_in[0];
  float* out = (float*)d_out;

  lca_kernel<<<dim3(NSIMB), dim3(512), 0, stream>>>(ff, out);
}

// Round 13
// 106.866 us; speedup vs baseline: 1.2418x; 1.2388x over previous
//
#include <hip/hip_runtime.h>
#include <cstdint>

// LCA model constants
#define T_STEPS 3000
#define S_SIMS  1000
#define D_DIM   16
#define NJ      (S_SIMS * D_DIM)          // 16000 flat (s,d) rows
#define ROW     (T_STEPS + 1)             // 3001 outputs per row
#define HALF_OUT ((long long)NJ * ROW)

#define NSIMB  250                        // blocks: 4 sims each, 64 rows each
#define NPROD  7                          // producer waves (r6-proven)
#define DEPTH  32                         // LDS noise ring slots (r6-proven)
#define BATCH  8                          // consumer speculation batch (r6-proven)
#define PAD_FLOATS 13000                  // LDS pad -> ~84KB total -> 1 block/CU
#define SQSTEP 0.03162277660168379f       // sqrt(0.001)

__device__ float g_ws_pre[(size_t)T_STEPS * NJ];  // [t][j] prefix only

// ---------------------------------------------------------------------------
// Threefry-2x32 (20 rounds), bit-exact vs jax._src.prng (partitionable mode)
// ---------------------------------------------------------------------------
__device__ __forceinline__ uint32_t rotl32(uint32_t v, uint32_t d) {
  return (v << d) | (v >> (32u - d));
}
__device__ __forceinline__ void threefry2x32(uint32_t k0, uint32_t k1,
                                             uint32_t& x0, uint32_t& x1) {
  uint32_t k2 = k0 ^ k1 ^ 0x1BD11BDAu;
  x0 += k0; x1 += k1;
#define TFR(r) { x0 += x1; x1 = rotl32(x1, r); x1 ^= x0; }
  TFR(13u) TFR(15u) TFR(26u) TFR(6u)
  x0 += k1; x1 += k2 + 1u;
  TFR(17u) TFR(29u) TFR(16u) TFR(24u)
  x0 += k2; x1 += k0 + 2u;
  TFR(13u) TFR(15u) TFR(26u) TFR(6u)
  x0 += k0; x1 += k1 + 3u;
  TFR(17u) TFR(29u) TFR(16u) TFR(24u)
  x0 += k1; x1 += k2 + 4u;
  TFR(13u) TFR(15u) TFR(26u) TFR(6u)
  x0 += k2; x1 += k0 + 5u;
#undef TFR
}

// bits -> N(0,1): jax.random.normal f32 path (XLA ErfInv32 / Giles), with
// log1p(-u*u) = ln2*log2((1-u)(1+u)) via HW log (validated r6: absmax 0.002).
__device__ __forceinline__ float bits_to_normal(uint32_t bits) {
  uint32_t fb = (bits >> 9) | 0x3f800000u;
  float f = __uint_as_float(fb) - 1.0f;
  const float lo = -0.99999994f;
  float u = f * 2.0f + lo;
  u = fmaxf(lo, u);
  float w = -0.6931471805599453f * __log2f((1.0f - u) * (1.0f + u));
  float p;
  if (w < 5.0f) {
    w = w - 2.5f;
    p = 2.81022636e-08f;
    p = fmaf(p, w, 3.43273939e-07f);
    p = fmaf(p, w, -3.5233877e-06f);
    p = fmaf(p, w, -4.39150654e-06f);
    p = fmaf(p, w, 0.00021858087f);
    p = fmaf(p, w, -0.00125372503f);
    p = fmaf(p, w, -0.00417768164f);
    p = fmaf(p, w, 0.246640727f);
    p = fmaf(p, w, 1.50140941f);
  } else {
    w = sqrtf(w) - 3.0f;
    p = -0.000200214257f;
    p = fmaf(p, w, 0.000100950558f);
    p = fmaf(p, w, 0.00134934322f);
    p = fmaf(p, w, -0.00367342844f);
    p = fmaf(p, w, 0.00573950773f);
    p = fmaf(p, w, -0.0076224613f);
    p = fmaf(p, w, 0.00943887047f);
    p = fmaf(p, w, 1.00167406f);
    p = fmaf(p, w, 2.83297682f);
  }
  return 1.41421356237f * (p * u);
}

// ---------------------------------------------------------------------------
// DPP reductions within each 16-lane row (one sim).
// ---------------------------------------------------------------------------
template <int CTRL>
__device__ __forceinline__ float dpp_movf(float v) {
  return __int_as_float(
      __builtin_amdgcn_update_dpp(0, __float_as_int(v), CTRL, 0xF, 0xF, true));
}
__device__ __forceinline__ float row16_sum(float a) {
  float s = a;
  s += dpp_movf<0xB1>(s);
  s += dpp_movf<0x4E>(s);
  s += dpp_movf<0x124>(s);
  s += dpp_movf<0x128>(s);
  return s;
}
__device__ __forceinline__ float row16_max(float a) {  // a >= 0
  float m = a;
  m = fmaxf(m, dpp_movf<0xB1>(m));
  m = fmaxf(m, dpp_movf<0x4E>(m));
  m = fmaxf(m, dpp_movf<0x124>(m));
  m = fmaxf(m, dpp_movf<0x128>(m));
  return m;
}

// ---------------------------------------------------------------------------
// Single kernel: keys prologue (LDS) -> r6 producer-consumer sim ->
// block-local self-fill of the block's own 64 output rows.
// No cross-block communication of any kind. LDS padded to ~84KB so only
// ONE block fits per CU (removes scheduler-packing unknown; producers
// saturate CU issue, a co-resident block would double step time).
// ---------------------------------------------------------------------------
__global__ __launch_bounds__(512) void lca_kernel(const float* __restrict__ ff,
                                                  float* __restrict__ out) {
  __shared__ uint2 sh_keys[T_STEPS];             // 24.0 KB
  __shared__ float sh_nbuf[DEPTH][64];           //  8.2 KB
  __shared__ float sh_pad[PAD_FLOATS];           // 52.0 KB occupancy pad
  __shared__ volatile unsigned sh_prodc[NPROD];
  __shared__ volatile unsigned sh_cons;
  __shared__ volatile unsigned sh_done;
  __shared__ int sh_tf[4];

  const int tid  = threadIdx.x;
  const int lane = tid & 63;
  const int wid  = tid >> 6;
  const int j    = blockIdx.x * 64 + lane;       // s = j>>4, d = j&15

  // ---- prologue: all 3000 step keys into LDS (partitionable fold) ----
  for (int i = tid; i < T_STEPS; i += 512) {
    uint32_t x0 = 0u, x1 = (uint32_t)i;
    threefry2x32(0u, 42u, x0, x1);
    sh_keys[i] = make_uint2(x0, x1);
  }
  { volatile float* vp = sh_pad; vp[tid] = 0.0f; }   // keep pad alive
  if (tid < NPROD) sh_prodc[tid] = 0u;
  if (tid == 0) { sh_cons = 0u; sh_done = 0u; }
  __syncthreads();

  if (wid == 0) {
    // ============ consumer: LCA dynamics, batch-8 speculative (r6) ==========
    __builtin_amdgcn_s_setprio(1);
    const float ffv = ff[j];
    float pre = 0.0f, act = 0.0f;
    bool dead = false;
    int my_tf = T_STEPS;
    unsigned Rc = 0;   // steps < Rc are known produced

#define ENSURE(x)                                                     \
    while (Rc <= (unsigned)(x)) {                                     \
      unsigned mn = 0xffffffffu;                                      \
      for (int p_ = 0; p_ < NPROD; ++p_) {                            \
        unsigned lim = (unsigned)p_ + (unsigned)NPROD * sh_prodc[p_]; \
        if (lim < mn) mn = lim;                                       \
      }                                                               \
      Rc = mn;                                                        \
      if (Rc <= (unsigned)(x)) __builtin_amdgcn_s_sleep(2);           \
    }

    float n[BATCH], nn[BATCH], a[BATCH];
    ENSURE(BATCH - 1);
#pragma unroll
    for (int k = 0; k < BATCH; ++k) n[k] = sh_nbuf[k][lane];

    int t0 = 0;
    while (true) {
      if (lane == 0) sh_cons = (unsigned)(t0 + BATCH);
      const bool more = (t0 + BATCH < T_STEPS);
      if (more) {
        ENSURE(t0 + 2 * BATCH - 1);
#pragma unroll
        for (int k = 0; k < BATCH; ++k)
          nn[k] = sh_nbuf[(t0 + BATCH + k) & (DEPTH - 1)][lane];
      }

      float bmax = 0.0f;
      float* __restrict__ wsp = g_ws_pre + (size_t)t0 * NJ + j;
#pragma unroll
      for (int k = 0; k < BATCH; ++k) {
        float s  = row16_sum(act);
        float e1 = fmaf(-0.1f, pre, ffv);          // ff - leak*pre
        float e2 = fmaf(-0.1f, s - act, e1);       // - competition*(sum-self)
        pre = fmaf(e2, 0.01f, pre);                // + expr*dt
        pre = fmaf(n[k], SQSTEP, pre);             // + dw*sqrt(0.001)
        act = fmaxf(pre, 0.0f);
        a[k] = act;
        bmax = fmaxf(bmax, act);
        if (!dead) wsp[(size_t)k * NJ] = pre;
      }

      if (__any(bmax >= 1.0f)) {                   // rare: <=4x per wave
        bool found = dead;
        int ctf = 0;
#pragma unroll
        for (int k = 0; k < BATCH; ++k) {
          float m = row16_max(a[k]);               // row-uniform
          if (!found && m >= 1.0f) { found = true; ctf = t0 + k + 1; }
        }
        if (found && !dead) {                      // this row just crossed
          dead = true;
          my_tf = ctf;
          pre = -1e30f;                            // relu pins act=0 forever
          act = 0.0f;
        }
        if (__all(dead)) break;
      }

      if (!more) break;
#pragma unroll
      for (int k = 0; k < BATCH; ++k) n[k] = nn[k];
      t0 += BATCH;
    }
#undef ENSURE
    if ((lane & 15) == 0) sh_tf[lane >> 4] = my_tf;  // row-uniform, 1<=tf<=3000
    if (lane == 0) sh_done = 1u;
    __builtin_amdgcn_s_setprio(0);
  } else {
    // ============ producers: noise for t ≡ p (mod NPROD) (r6) ===============
    const int p = wid - 1;
    unsigned count = 0;
    bool quit = false;
    for (int t = p; t < T_STEPS; t += NPROD) {
      if (sh_done) break;
      uint2 k = sh_keys[t];
      uint32_t x0 = 0u, x1 = (uint32_t)j;
      threefry2x32(k.x, k.y, x0, x1);
      float nv = bits_to_normal(x0 ^ x1);
      if (t >= DEPTH) {
        while (true) {
          if (sh_done) { quit = true; break; }
          unsigned pc = sh_cons;
          if ((unsigned)t <= pc + (DEPTH - 1)) break;
          __builtin_amdgcn_s_sleep(4);
        }
        if (quit) break;
      }
      sh_nbuf[t & (DEPTH - 1)][lane] = nv;
      asm volatile("s_waitcnt lgkmcnt(0)" ::: "memory");
      ++count;
      if (lane == 0) sh_prodc[p] = count;
    }
  }

  __syncthreads();   // sh_tf visible; consumer's ws writes drained (vmcnt(0))

  // ============ self-fill: wave wid fills rows [wid*8, wid*8+8) =============
  const int r0 = wid * 8;
#pragma unroll 1
  for (int r = 0; r < 8; ++r) {
    const int jr = blockIdx.x * 64 + r0 + r;
    const int tf = sh_tf[(r0 + r) >> 4];
    float* __restrict__ pre_out = out + (size_t)jr * ROW;
    float* __restrict__ act_out = pre_out + HALF_OUT;
    const float vlast = g_ws_pre[(size_t)(tf - 1) * NJ + jr];  // broadcast read
    // prefix (incl idx=0): out[idx] = idx==0 ? 0 : ws[idx-1]
    for (int idx = lane; idx <= tf; idx += 64) {
      float v = (idx == 0) ? 0.0f : g_ws_pre[(size_t)(idx - 1) * NJ + jr];
      pre_out[idx] = v;
      act_out[idx] = fmaxf(v, 0.0f);
    }
    // frozen tail: pure streaming stores, no loads
    const float va = fmaxf(vlast, 0.0f);
    for (int idx = tf + 1 + lane; idx <= T_STEPS; idx += 64) {
      pre_out[idx] = vlast;
      act_out[idx] = va;
    }
  }
}

// ---------------------------------------------------------------------------
extern "C" void kernel_launch(void* const* d_in, const int* in_sizes, int n_in,
                              void* d_out, int out_size, void* d_ws, size_t ws_size,
                              hipStream_t stream) {
  const float* ff = (const float*)d_in[0];
  float* out = (float*)d_out;

  lca_kernel<<<dim3(NSIMB), dim3(512), 0, stream>>>(ff, out);
}